// Round 3
// baseline (595.983 us; speedup 1.0000x reference)
//
#include <hip/hip_runtime.h>

typedef unsigned short u16;
typedef unsigned int   u32;

#define BTOT 32768
#define BPB  4             // batch elems per block; 64 threads = ONE wave
#define XS   20            // xbuf row stride (floats)
#define XBS  260           // xbuf per-b stride (13*20), 16B-aligned, %32=4 -> conflict-free
#define MU_OFF   22151168  // 32768*4*169
#define LV_OFF   28966912  // + 32768*13*16

// out[j] = B[bbase+j] + sum_m in[m] * W[wbase + j*16 + m]; W/B indices wave-uniform -> s_load
__device__ __forceinline__ void mv16f(const float* __restrict__ W, int wbase,
                                      const float* __restrict__ B, int bbase,
                                      const float* in, float* out) {
#pragma unroll
    for (int j = 0; j < 16; j++) {
        float s = B[bbase + j];
#pragma unroll
        for (int m = 0; m < 16; m++) s += in[m] * W[wbase + j*16 + m];
        out[j] = s;
    }
}

// Round-3 change: ROLL the layer loop and decoder loop (#pragma unroll 1).
// Fully-unrolled body was ~130 KB of code vs 32 KB I$ -> staggered single
// waves thrashed the instruction cache (explains R1/R2: dur insensitive to
// 2x data-traffic change, VALUBusy 29%, FETCH excess ~ I-fetch volume).
// Rolled body ~20 KB fits I$. BN params prefetched so the rolled loop body
// has no global-latency dependence (weights are K$-cached s_loads).
__global__ __launch_bounds__(64, 3) void vae_kernel(
    const float* __restrict__ adj,  const float* __restrict__ initw,
    const float* __restrict__ epsp,
    const float* __restrict__ w0,   const float* __restrict__ b0,
    const float* __restrict__ w1,   const float* __restrict__ b1,
    const float* __restrict__ big,  const float* __restrict__ bib,
    const float* __restrict__ bim,  const float* __restrict__ biv,
    const float* __restrict__ bog,  const float* __restrict__ bob,
    const float* __restrict__ bom,  const float* __restrict__ bov,
    const float* __restrict__ fc1w, const float* __restrict__ fc1b,
    const float* __restrict__ fc2w, const float* __restrict__ fc2b,
    const float* __restrict__ decw, const float* __restrict__ decb,
    float* __restrict__ out)
{
    __shared__ __align__(16) float stage[2704];      // 10816 B: adj in, then mu/lv, then recon
    __shared__ __align__(16) float xbuf[BPB * XBS];  //  4160 B: x rows / decoder temp rows

    const int tid = threadIdx.x;
    const int b   = tid >> 4;          // local batch elem 0..3
    const int n   = tid & 15;          // node row; active if n < 13
    const bool act = (n < 13);
    const int nn  = act ? n : 0;

    // ---- phase 1: coalesced adj -> LDS (676 float4 = 10 full rounds + 36) ----
    {
        const float4* src4 = (const float4*)(adj + (size_t)blockIdx.x * 2704);
        float4* st4 = (float4*)stage;
#pragma unroll
        for (int r = 0; r < 10; r++) st4[tid + 64*r] = src4[tid + 64*r];
        if (tid < 36) st4[tid + 640] = src4[tid + 640];
    }

    // ---- BN affine prefetch (overlaps adj staging latency): 20 regs ----
    float si[4], ti[4], so[4], to[4], ep[4];
#pragma unroll
    for (int l = 0; l < 4; l++) {
        const int o = l*13 + nn;
        float s0 = big[o] * rsqrtf(biv[o] + 1e-5f);
        si[l] = s0;
        ti[l] = bib[o] - bim[o] * s0;
        float s1 = bog[o] * rsqrtf(bov[o] + 1e-5f);
        so[l] = s1;
        to[l] = bob[o] - bom[o] * s1;
        ep[l] = 1.f + epsp[l];
    }
    __syncthreads();

    // ---- adj slice -> 52 regs (from LDS; compiler re-reads hit LDS, not HBM) ----
    float A[4][13];
    {
        const float* ap = stage + b*676 + nn*13;
#pragma unroll
        for (int i = 0; i < 4; i++)
#pragma unroll
            for (int m = 0; m < 13; m++)
                A[i][m] = ap[i*169 + m];
    }

    float* myrow = xbuf + b * XBS + n * XS;
    const float* brow = xbuf + b * XBS;

    // ---- init: x = (sum_i adj) @ W ----
    float xr[16];
    {
        float as[13];
#pragma unroll
        for (int m = 0; m < 13; m++) as[m] = A[0][m] + A[1][m] + A[2][m] + A[3][m];
#pragma unroll
        for (int j = 0; j < 16; j++) xr[j] = 0.f;
#pragma unroll
        for (int m = 0; m < 13; m++)
#pragma unroll
            for (int j = 0; j < 16; j++)
                xr[j] += as[m] * initw[m*16 + j];
    }

    if (act) {
        float4* w = (float4*)myrow;
        w[0] = make_float4(xr[0],xr[1],xr[2],xr[3]);
        w[1] = make_float4(xr[4],xr[5],xr[6],xr[7]);
        w[2] = make_float4(xr[8],xr[9],xr[10],xr[11]);
        w[3] = make_float4(xr[12],xr[13],xr[14],xr[15]);
    }
    __syncthreads();

    // ---- 4 GIN layers (ROLLED: one body in I$, 4 passes) ----
#pragma unroll 1
    for (int l = 0; l < 4; l++) {
        const int wb = l << 8;         // l*256
        const int bb = l << 4;         // l*16

        // agg = (1+eps)*x + neighbor   (reads all rows of this b from LDS)
        float acc[16];
#pragma unroll
        for (int j = 0; j < 16; j++) acc[j] = ep[l] * xr[j];
#pragma unroll
        for (int m = 0; m < 13; m++) {
            const float4* rp = (const float4*)(brow + m * XS);
            float4 r0 = rp[0], r1 = rp[1], r2 = rp[2], r3 = rp[3];
            float a0 = A[0][m], a1 = A[1][m], a2 = A[2][m], a3 = A[3][m];
            acc[0]  += a0*r0.x; acc[1]  += a0*r0.y; acc[2]  += a0*r0.z; acc[3]  += a0*r0.w;
            acc[4]  += a1*r1.x; acc[5]  += a1*r1.y; acc[6]  += a1*r1.z; acc[7]  += a1*r1.w;
            acc[8]  += a2*r2.x; acc[9]  += a2*r2.y; acc[10] += a2*r2.z; acc[11] += a2*r2.w;
            acc[12] += a3*r3.x; acc[13] += a3*r3.y; acc[14] += a3*r3.z; acc[15] += a3*r3.w;
        }

        // h1 = leaky(bn_in(agg @ w0^T + b0))
        float h[16];
        mv16f(w0, wb, b0, bb, acc, h);
#pragma unroll
        for (int j = 0; j < 16; j++) {
            float v = si[l] * h[j] + ti[l];
            h[j] = (v >= 0.f) ? v : 0.01f * v;
        }
        // x = leaky(bn_out(h @ w1^T + b1))
        mv16f(w1, wb, b1, bb, h, xr);
#pragma unroll
        for (int j = 0; j < 16; j++) {
            float v = so[l] * xr[j] + to[l];
            xr[j] = (v >= 0.f) ? v : 0.01f * v;
        }

        __syncthreads();               // all lanes done reading old x (1-wave: ~free)
        if (l < 3 && act) {
            float4* w = (float4*)myrow;
            w[0] = make_float4(xr[0],xr[1],xr[2],xr[3]);
            w[1] = make_float4(xr[4],xr[5],xr[6],xr[7]);
            w[2] = make_float4(xr[8],xr[9],xr[10],xr[11]);
            w[3] = make_float4(xr[12],xr[13],xr[14],xr[15]);
        }
        __syncthreads();               // new x visible; also: all stage(adj) reads done
    }

    // ---- mu / logvar (row-local), staged through LDS for coalesced store ----
    float mu[16], lv[16];
    mv16f(fc1w, 0, fc1b, 0, xr, mu);
    mv16f(fc2w, 0, fc2b, 0, xr, lv);
    if (act) {
        float4* ms = (float4*)(stage + b*208 + n*16);        // [0..832)
        ms[0] = make_float4(mu[0],mu[1],mu[2],mu[3]);
        ms[1] = make_float4(mu[4],mu[5],mu[6],mu[7]);
        ms[2] = make_float4(mu[8],mu[9],mu[10],mu[11]);
        ms[3] = make_float4(mu[12],mu[13],mu[14],mu[15]);
        float4* ls = (float4*)(stage + 832 + b*208 + n*16);  // [832..1664)
        ls[0] = make_float4(lv[0],lv[1],lv[2],lv[3]);
        ls[1] = make_float4(lv[4],lv[5],lv[6],lv[7]);
        ls[2] = make_float4(lv[8],lv[9],lv[10],lv[11]);
        ls[3] = make_float4(lv[12],lv[13],lv[14],lv[15]);
    }
    __syncthreads();
    {
        // block's mu region = 832 contiguous floats = 208 float4 (3 rounds + 16)
        float4* mo4 = (float4*)(out + MU_OFF + (size_t)blockIdx.x * 832);
        float4* lo4 = (float4*)(out + LV_OFF + (size_t)blockIdx.x * 832);
        const float4* s4 = (const float4*)stage;
#pragma unroll
        for (int r = 0; r < 3; r++) mo4[tid + 64*r] = s4[tid + 64*r];
        if (tid < 16) mo4[tid + 192] = s4[tid + 192];
#pragma unroll
        for (int r = 0; r < 3; r++) lo4[tid + 64*r] = s4[208 + tid + 64*r];
        if (tid < 16) lo4[tid + 192] = s4[208 + tid + 192];
    }
    // no barrier here: decoder's first inner barrier orders stage reuse,
    // and the mu/lv global stores drain under the k=0 mv16f compute.

    // ---- decoder: z = mu (ROLLED); recon staged in LDS, flushed at the end ----
#pragma unroll 1
    for (int k = 0; k < 4; k++) {
        float tr[16];
        mv16f(decw, k << 8, decb, k << 4, mu, tr);   // temp row n

        if (act) {
            float4* w = (float4*)myrow;
            w[0] = make_float4(tr[0],tr[1],tr[2],tr[3]);
            w[1] = make_float4(tr[4],tr[5],tr[6],tr[7]);
            w[2] = make_float4(tr[8],tr[9],tr[10],tr[11]);
            w[3] = make_float4(tr[12],tr[13],tr[14],tr[15]);
        }
        __syncthreads();               // temp rows visible (also: k=0 guards stage reuse)

        float r[13];
#pragma unroll
        for (int m = 0; m < 13; m++) {
            const float4* rp = (const float4*)(brow + m * XS);
            float4 r0 = rp[0], r1 = rp[1], r2 = rp[2], r3 = rp[3];
            r[m] = tr[0]*r0.x + tr[1]*r0.y + tr[2]*r0.z + tr[3]*r0.w
                 + tr[4]*r1.x + tr[5]*r1.y + tr[6]*r1.z + tr[7]*r1.w
                 + tr[8]*r2.x + tr[9]*r2.y + tr[10]*r2.z + tr[11]*r2.w
                 + tr[12]*r3.x + tr[13]*r3.y + tr[14]*r3.z + tr[15]*r3.w;
        }
        if (act) {
            float* rs = stage + b*676 + k*169 + n*13;
#pragma unroll
            for (int m = 0; m < 13; m++) rs[m] = fmaxf(r[m], 0.f);
        }
        __syncthreads();               // readers done before next k overwrites temp
    }

    // ---- coalesced recon flush: 2704 contiguous floats = 676 float4 ----
    {
        float4* ro4 = (float4*)(out + (size_t)blockIdx.x * 2704);
        const float4* s4 = (const float4*)stage;
#pragma unroll
        for (int r = 0; r < 10; r++) ro4[tid + 64*r] = s4[tid + 64*r];
        if (tid < 36) ro4[tid + 640] = s4[tid + 640];
    }
}

extern "C" void kernel_launch(void* const* d_in, const int* in_sizes, int n_in,
                              void* d_out, int out_size, void* d_ws, size_t ws_size,
                              hipStream_t stream) {
    vae_kernel<<<dim3(BTOT/BPB), dim3(64), 0, stream>>>(
        (const float*)d_in[0],  (const float*)d_in[1],  (const float*)d_in[2],
        (const float*)d_in[3],  (const float*)d_in[4],  (const float*)d_in[5],
        (const float*)d_in[6],  (const float*)d_in[7],  (const float*)d_in[8],
        (const float*)d_in[9],  (const float*)d_in[10], (const float*)d_in[11],
        (const float*)d_in[12], (const float*)d_in[13], (const float*)d_in[14],
        (const float*)d_in[15], (const float*)d_in[16], (const float*)d_in[17],
        (const float*)d_in[18], (const float*)d_in[19], (const float*)d_in[20],
        (float*)d_out);
}

// Round 4
// 469.427 us; speedup vs baseline: 1.2696x; 1.2696x over previous
//
#include <hip/hip_runtime.h>

typedef unsigned short u16;
typedef unsigned int   u32;

#define BTOT 32768
#define BPB  16
#define XS   20            // xbuf row stride (floats)
#define XBS  260           // xbuf per-b stride (13*20), 16B-aligned, %32=4 -> conflict-free
#define MU_OFF   22151168  // 32768*4*169
#define LV_OFF   28966912  // + 32768*13*16

// out[j] = B[bbase+j] + sum_m in[m] * W[wbase + j*16 + m]; W/B indices wave-uniform -> s_load
__device__ __forceinline__ void mv16f(const float* __restrict__ W, int wbase,
                                      const float* __restrict__ B, int bbase,
                                      const float* in, float* out) {
#pragma unroll
    for (int j = 0; j < 16; j++) {
        float s = B[bbase + j];
#pragma unroll
        for (int m = 0; m < 16; m++) s += in[m] * W[wbase + j*16 + m];
        out[j] = s;
    }
}

// R4 = R0 structure (256-thr blocks, best measured: 312us) + CLEANLY rolled
// layer/decoder loops. Theory: fully-unrolled ~100KB text vs 32KB L1I makes
// I-fetch the shared per-CU bottleneck (R1: 15 waves/CU resident yet VALU 27%
// -> stall is a shared pipe; R0's 4-wave lockstep shares the fetch stream ->
// 25% faster than staggered singles; traffic varied 4x with ~0 dur change).
// R3's roll failed via rule #20 (runtime-indexed si[l]/ti[l] arrays -> scratch,
// +10K instr/wave). Here: NO runtime-indexed private arrays -- BN scalars are
// recomputed in-loop from global (L2-cached, lane-varying addr), eps s-loaded.
__global__ __launch_bounds__(256, 2) void vae_kernel(
    const float* __restrict__ adj,  const float* __restrict__ initw,
    const float* __restrict__ epsp,
    const float* __restrict__ w0,   const float* __restrict__ b0,
    const float* __restrict__ w1,   const float* __restrict__ b1,
    const float* __restrict__ big,  const float* __restrict__ bib,
    const float* __restrict__ bim,  const float* __restrict__ biv,
    const float* __restrict__ bog,  const float* __restrict__ bob,
    const float* __restrict__ bom,  const float* __restrict__ bov,
    const float* __restrict__ fc1w, const float* __restrict__ fc1b,
    const float* __restrict__ fc2w, const float* __restrict__ fc2b,
    const float* __restrict__ decw, const float* __restrict__ decb,
    float* __restrict__ out)
{
    __shared__ float xbuf[BPB * XBS];   // 16640 B

    const int tid = threadIdx.x;
    const int b   = tid >> 4;          // local batch elem 0..15
    const int n   = tid & 15;          // node row; active if n < 13
    const bool act = (n < 13);
    const int nn  = act ? n : 0;
    const size_t gb = (size_t)blockIdx.x * BPB + b;

    float* myrow = xbuf + b * XBS + n * XS;
    const float* brow = xbuf + b * XBS;

    // ---- adj slice -> 52 regs ----
    float A[4][13];
    {
        const float* ap = adj + gb * 676 + nn * 13;
#pragma unroll
        for (int i = 0; i < 4; i++)
#pragma unroll
            for (int m = 0; m < 13; m++)
                A[i][m] = ap[i*169 + m];
    }

    // ---- init: x = (sum_i adj) @ W ----
    float xr[16];
    {
        float as[13];
#pragma unroll
        for (int m = 0; m < 13; m++) as[m] = A[0][m] + A[1][m] + A[2][m] + A[3][m];
#pragma unroll
        for (int j = 0; j < 16; j++) xr[j] = 0.f;
#pragma unroll
        for (int m = 0; m < 13; m++)
#pragma unroll
            for (int j = 0; j < 16; j++)
                xr[j] += as[m] * initw[m*16 + j];
    }

    if (act) {
        float4* w = (float4*)myrow;
        w[0] = make_float4(xr[0],xr[1],xr[2],xr[3]);
        w[1] = make_float4(xr[4],xr[5],xr[6],xr[7]);
        w[2] = make_float4(xr[8],xr[9],xr[10],xr[11]);
        w[3] = make_float4(xr[12],xr[13],xr[14],xr[15]);
    }
    __syncthreads();

    // ---- 4 GIN layers (ROLLED; all private arrays statically indexed) ----
#pragma unroll 1
    for (int l = 0; l < 4; l++) {
        // BN scalars recomputed in-loop: lane-varying vector loads, L2-cached.
        const int o = l*13 + nn;
        const float si = big[o] * rsqrtf(biv[o] + 1e-5f);
        const float ti = bib[o] - bim[o] * si;
        const float so = bog[o] * rsqrtf(bov[o] + 1e-5f);
        const float to = bob[o] - bom[o] * so;
        const float ep = 1.f + epsp[l];
        const int wb = l << 8;         // l*256
        const int bb = l << 4;         // l*16

        // agg = (1+eps)*x + neighbor   (reads all rows of this b from LDS)
        float acc[16];
#pragma unroll
        for (int j = 0; j < 16; j++) acc[j] = ep * xr[j];
#pragma unroll
        for (int m = 0; m < 13; m++) {
            const float4* rp = (const float4*)(brow + m * XS);
            float4 r0 = rp[0], r1 = rp[1], r2 = rp[2], r3 = rp[3];
            float a0 = A[0][m], a1 = A[1][m], a2 = A[2][m], a3 = A[3][m];
            acc[0]  += a0*r0.x; acc[1]  += a0*r0.y; acc[2]  += a0*r0.z; acc[3]  += a0*r0.w;
            acc[4]  += a1*r1.x; acc[5]  += a1*r1.y; acc[6]  += a1*r1.z; acc[7]  += a1*r1.w;
            acc[8]  += a2*r2.x; acc[9]  += a2*r2.y; acc[10] += a2*r2.z; acc[11] += a2*r2.w;
            acc[12] += a3*r3.x; acc[13] += a3*r3.y; acc[14] += a3*r3.z; acc[15] += a3*r3.w;
        }

        // h1 = leaky(bn_in(agg @ w0^T + b0))
        float h[16];
        mv16f(w0, wb, b0, bb, acc, h);
#pragma unroll
        for (int j = 0; j < 16; j++) {
            float v = si * h[j] + ti;
            h[j] = (v >= 0.f) ? v : 0.01f * v;
        }
        // x = leaky(bn_out(h @ w1^T + b1))
        mv16f(w1, wb, b1, bb, h, xr);
#pragma unroll
        for (int j = 0; j < 16; j++) {
            float v = so * xr[j] + to;
            xr[j] = (v >= 0.f) ? v : 0.01f * v;
        }

        __syncthreads();               // all lanes done reading old x
        if (l < 3 && act) {
            float4* w = (float4*)myrow;
            w[0] = make_float4(xr[0],xr[1],xr[2],xr[3]);
            w[1] = make_float4(xr[4],xr[5],xr[6],xr[7]);
            w[2] = make_float4(xr[8],xr[9],xr[10],xr[11]);
            w[3] = make_float4(xr[12],xr[13],xr[14],xr[15]);
        }
        __syncthreads();               // new x visible
    }

    // ---- mu / logvar (row-local) ----
    float mu[16], lv[16];
    mv16f(fc1w, 0, fc1b, 0, xr, mu);
    mv16f(fc2w, 0, fc2b, 0, xr, lv);
    if (act) {
        float4* mo = (float4*)(out + MU_OFF + gb*208 + n*16);
        mo[0] = make_float4(mu[0],mu[1],mu[2],mu[3]);
        mo[1] = make_float4(mu[4],mu[5],mu[6],mu[7]);
        mo[2] = make_float4(mu[8],mu[9],mu[10],mu[11]);
        mo[3] = make_float4(mu[12],mu[13],mu[14],mu[15]);
        float4* lo = (float4*)(out + LV_OFF + gb*208 + n*16);
        lo[0] = make_float4(lv[0],lv[1],lv[2],lv[3]);
        lo[1] = make_float4(lv[4],lv[5],lv[6],lv[7]);
        lo[2] = make_float4(lv[8],lv[9],lv[10],lv[11]);
        lo[3] = make_float4(lv[12],lv[13],lv[14],lv[15]);
    }

    // ---- decoder: z = mu (ROLLED) ----
#pragma unroll 1
    for (int k = 0; k < 4; k++) {
        float tr[16];
        mv16f(decw, k << 8, decb, k << 4, mu, tr);   // temp row n

        if (act) {
            float4* w = (float4*)myrow;
            w[0] = make_float4(tr[0],tr[1],tr[2],tr[3]);
            w[1] = make_float4(tr[4],tr[5],tr[6],tr[7]);
            w[2] = make_float4(tr[8],tr[9],tr[10],tr[11]);
            w[3] = make_float4(tr[12],tr[13],tr[14],tr[15]);
        }
        __syncthreads();               // temp rows visible

        float r[13];
#pragma unroll
        for (int m = 0; m < 13; m++) {
            const float4* rp = (const float4*)(brow + m * XS);
            float4 r0 = rp[0], r1 = rp[1], r2 = rp[2], r3 = rp[3];
            r[m] = tr[0]*r0.x + tr[1]*r0.y + tr[2]*r0.z + tr[3]*r0.w
                 + tr[4]*r1.x + tr[5]*r1.y + tr[6]*r1.z + tr[7]*r1.w
                 + tr[8]*r2.x + tr[9]*r2.y + tr[10]*r2.z + tr[11]*r2.w
                 + tr[12]*r3.x + tr[13]*r3.y + tr[14]*r3.z + tr[15]*r3.w;
        }
        if (act) {
            float* ro = out + gb*676 + (size_t)k*169 + n*13;
#pragma unroll
            for (int m = 0; m < 13; m++) ro[m] = fmaxf(r[m], 0.f);
        }
        __syncthreads();               // readers done before next k overwrites
    }
}

extern "C" void kernel_launch(void* const* d_in, const int* in_sizes, int n_in,
                              void* d_out, int out_size, void* d_ws, size_t ws_size,
                              hipStream_t stream) {
    vae_kernel<<<dim3(BTOT/BPB), dim3(256), 0, stream>>>(
        (const float*)d_in[0],  (const float*)d_in[1],  (const float*)d_in[2],
        (const float*)d_in[3],  (const float*)d_in[4],  (const float*)d_in[5],
        (const float*)d_in[6],  (const float*)d_in[7],  (const float*)d_in[8],
        (const float*)d_in[9],  (const float*)d_in[10], (const float*)d_in[11],
        (const float*)d_in[12], (const float*)d_in[13], (const float*)d_in[14],
        (const float*)d_in[15], (const float*)d_in[16], (const float*)d_in[17],
        (const float*)d_in[18], (const float*)d_in[19], (const float*)d_in[20],
        (float*)d_out);
}

// Round 5
// 352.141 us; speedup vs baseline: 1.6925x; 1.3331x over previous
//
#include <hip/hip_runtime.h>

typedef unsigned short u16;
typedef unsigned int   u32;

#define BTOT 32768
#define BPB  4             // batch elems per block; 64 threads = ONE wave
#define XS   20            // xbuf row stride (floats)
#define XBS  260           // xbuf per-b stride (13*20), 16B-aligned, %32=4 -> conflict-free
#define MU_OFF   22151168  // 32768*4*169
#define LV_OFF   28966912  // + 32768*13*16

// out[j] = B[bbase+j] + sum_m in[m] * W[wbase + j*16 + m]; W/B indices wave-uniform -> s_load
__device__ __forceinline__ void mv16f(const float* __restrict__ W, int wbase,
                                      const float* __restrict__ B, int bbase,
                                      const float* in, float* out) {
#pragma unroll
    for (int j = 0; j < 16; j++) {
        float s = B[bbase + j];
#pragma unroll
        for (int m = 0; m < 16; m++) s += in[m] * W[wbase + j*16 + m];
        out[j] = s;
    }
}

// R5 = R4's clean rolled body (small text, ~20KB, fits L1I; no runtime-indexed
// private arrays) x R1's single-wave launch (64-thr blocks -> ~15 independent
// streams/CU). Factorization of R0-R4: unrolled text thrashed L1I for staggered
// waves (R1/R2 slow at high occ); lockstep 256-thr blocks fixed I-fetch but
// exposed barrier drains at ~1.9 blocks/CU (R0/R4). Rolled+many-streams is the
// untested quadrant (R3 was contaminated by rule-#20 scratch arrays).
// launch_bounds(64,3): VGPR cap 170 so regalloc keeps A[4][13] resident
// (R1's (64,4) pushed VGPR to 64 via remat -> 5x adj re-reads).
__global__ __launch_bounds__(64, 3) void vae_kernel(
    const float* __restrict__ adj,  const float* __restrict__ initw,
    const float* __restrict__ epsp,
    const float* __restrict__ w0,   const float* __restrict__ b0,
    const float* __restrict__ w1,   const float* __restrict__ b1,
    const float* __restrict__ big,  const float* __restrict__ bib,
    const float* __restrict__ bim,  const float* __restrict__ biv,
    const float* __restrict__ bog,  const float* __restrict__ bob,
    const float* __restrict__ bom,  const float* __restrict__ bov,
    const float* __restrict__ fc1w, const float* __restrict__ fc1b,
    const float* __restrict__ fc2w, const float* __restrict__ fc2b,
    const float* __restrict__ decw, const float* __restrict__ decb,
    float* __restrict__ out)
{
    __shared__ float xbuf[BPB * XBS];   // 4160 B

    const int tid = threadIdx.x;
    const int b   = tid >> 4;          // local batch elem 0..3
    const int n   = tid & 15;          // node row; active if n < 13
    const bool act = (n < 13);
    const int nn  = act ? n : 0;
    const size_t gb = (size_t)blockIdx.x * BPB + b;

    float* myrow = xbuf + b * XBS + n * XS;
    const float* brow = xbuf + b * XBS;

    // ---- adj slice -> 52 regs ----
    float A[4][13];
    {
        const float* ap = adj + gb * 676 + nn * 13;
#pragma unroll
        for (int i = 0; i < 4; i++)
#pragma unroll
            for (int m = 0; m < 13; m++)
                A[i][m] = ap[i*169 + m];
    }

    // ---- init: x = (sum_i adj) @ W ----
    float xr[16];
    {
        float as[13];
#pragma unroll
        for (int m = 0; m < 13; m++) as[m] = A[0][m] + A[1][m] + A[2][m] + A[3][m];
#pragma unroll
        for (int j = 0; j < 16; j++) xr[j] = 0.f;
#pragma unroll
        for (int m = 0; m < 13; m++)
#pragma unroll
            for (int j = 0; j < 16; j++)
                xr[j] += as[m] * initw[m*16 + j];
    }

    if (act) {
        float4* w = (float4*)myrow;
        w[0] = make_float4(xr[0],xr[1],xr[2],xr[3]);
        w[1] = make_float4(xr[4],xr[5],xr[6],xr[7]);
        w[2] = make_float4(xr[8],xr[9],xr[10],xr[11]);
        w[3] = make_float4(xr[12],xr[13],xr[14],xr[15]);
    }
    __syncthreads();                   // single-wave block: ~free

    // ---- 4 GIN layers (ROLLED; all private arrays statically indexed) ----
#pragma unroll 1
    for (int l = 0; l < 4; l++) {
        // BN scalars recomputed in-loop: lane-varying vector loads, L2/L3-cached.
        const int o = l*13 + nn;
        const float si = big[o] * rsqrtf(biv[o] + 1e-5f);
        const float ti = bib[o] - bim[o] * si;
        const float so = bog[o] * rsqrtf(bov[o] + 1e-5f);
        const float to = bob[o] - bom[o] * so;
        const float ep = 1.f + epsp[l];
        const int wb = l << 8;         // l*256
        const int bb = l << 4;         // l*16

        // agg = (1+eps)*x + neighbor   (reads all rows of this b from LDS)
        float acc[16];
#pragma unroll
        for (int j = 0; j < 16; j++) acc[j] = ep * xr[j];
#pragma unroll
        for (int m = 0; m < 13; m++) {
            const float4* rp = (const float4*)(brow + m * XS);
            float4 r0 = rp[0], r1 = rp[1], r2 = rp[2], r3 = rp[3];
            float a0 = A[0][m], a1 = A[1][m], a2 = A[2][m], a3 = A[3][m];
            acc[0]  += a0*r0.x; acc[1]  += a0*r0.y; acc[2]  += a0*r0.z; acc[3]  += a0*r0.w;
            acc[4]  += a1*r1.x; acc[5]  += a1*r1.y; acc[6]  += a1*r1.z; acc[7]  += a1*r1.w;
            acc[8]  += a2*r2.x; acc[9]  += a2*r2.y; acc[10] += a2*r2.z; acc[11] += a2*r2.w;
            acc[12] += a3*r3.x; acc[13] += a3*r3.y; acc[14] += a3*r3.z; acc[15] += a3*r3.w;
        }

        // h1 = leaky(bn_in(agg @ w0^T + b0))
        float h[16];
        mv16f(w0, wb, b0, bb, acc, h);
#pragma unroll
        for (int j = 0; j < 16; j++) {
            float v = si * h[j] + ti;
            h[j] = fmaxf(v, 0.01f * v);
        }
        // x = leaky(bn_out(h @ w1^T + b1))
        mv16f(w1, wb, b1, bb, h, xr);
#pragma unroll
        for (int j = 0; j < 16; j++) {
            float v = so * xr[j] + to;
            xr[j] = fmaxf(v, 0.01f * v);
        }

        __syncthreads();               // all lanes done reading old x
        if (l < 3 && act) {
            float4* w = (float4*)myrow;
            w[0] = make_float4(xr[0],xr[1],xr[2],xr[3]);
            w[1] = make_float4(xr[4],xr[5],xr[6],xr[7]);
            w[2] = make_float4(xr[8],xr[9],xr[10],xr[11]);
            w[3] = make_float4(xr[12],xr[13],xr[14],xr[15]);
        }
        __syncthreads();               // new x visible
    }

    // ---- mu / logvar (row-local) ----
    float mu[16], lv[16];
    mv16f(fc1w, 0, fc1b, 0, xr, mu);
    mv16f(fc2w, 0, fc2b, 0, xr, lv);
    if (act) {
        float4* mo = (float4*)(out + MU_OFF + gb*208 + n*16);
        mo[0] = make_float4(mu[0],mu[1],mu[2],mu[3]);
        mo[1] = make_float4(mu[4],mu[5],mu[6],mu[7]);
        mo[2] = make_float4(mu[8],mu[9],mu[10],mu[11]);
        mo[3] = make_float4(mu[12],mu[13],mu[14],mu[15]);
        float4* lo = (float4*)(out + LV_OFF + gb*208 + n*16);
        lo[0] = make_float4(lv[0],lv[1],lv[2],lv[3]);
        lo[1] = make_float4(lv[4],lv[5],lv[6],lv[7]);
        lo[2] = make_float4(lv[8],lv[9],lv[10],lv[11]);
        lo[3] = make_float4(lv[12],lv[13],lv[14],lv[15]);
    }

    // ---- decoder: z = mu (ROLLED) ----
#pragma unroll 1
    for (int k = 0; k < 4; k++) {
        float tr[16];
        mv16f(decw, k << 8, decb, k << 4, mu, tr);   // temp row n

        if (act) {
            float4* w = (float4*)myrow;
            w[0] = make_float4(tr[0],tr[1],tr[2],tr[3]);
            w[1] = make_float4(tr[4],tr[5],tr[6],tr[7]);
            w[2] = make_float4(tr[8],tr[9],tr[10],tr[11]);
            w[3] = make_float4(tr[12],tr[13],tr[14],tr[15]);
        }
        __syncthreads();               // temp rows visible

        float r[13];
#pragma unroll
        for (int m = 0; m < 13; m++) {
            const float4* rp = (const float4*)(brow + m * XS);
            float4 r0 = rp[0], r1 = rp[1], r2 = rp[2], r3 = rp[3];
            r[m] = tr[0]*r0.x + tr[1]*r0.y + tr[2]*r0.z + tr[3]*r0.w
                 + tr[4]*r1.x + tr[5]*r1.y + tr[6]*r1.z + tr[7]*r1.w
                 + tr[8]*r2.x + tr[9]*r2.y + tr[10]*r2.z + tr[11]*r2.w
                 + tr[12]*r3.x + tr[13]*r3.y + tr[14]*r3.z + tr[15]*r3.w;
        }
        if (act) {
            float* ro = out + gb*676 + (size_t)k*169 + n*13;
#pragma unroll
            for (int m = 0; m < 13; m++) ro[m] = fmaxf(r[m], 0.f);
        }
        __syncthreads();               // readers done before next k overwrites
    }
}

extern "C" void kernel_launch(void* const* d_in, const int* in_sizes, int n_in,
                              void* d_out, int out_size, void* d_ws, size_t ws_size,
                              hipStream_t stream) {
    vae_kernel<<<dim3(BTOT/BPB), dim3(64), 0, stream>>>(
        (const float*)d_in[0],  (const float*)d_in[1],  (const float*)d_in[2],
        (const float*)d_in[3],  (const float*)d_in[4],  (const float*)d_in[5],
        (const float*)d_in[6],  (const float*)d_in[7],  (const float*)d_in[8],
        (const float*)d_in[9],  (const float*)d_in[10], (const float*)d_in[11],
        (const float*)d_in[12], (const float*)d_in[13], (const float*)d_in[14],
        (const float*)d_in[15], (const float*)d_in[16], (const float*)d_in[17],
        (const float*)d_in[18], (const float*)d_in[19], (const float*)d_in[20],
        (float*)d_out);
}